// Round 1
// baseline (531.493 us; speedup 1.0000x reference)
//
#include <hip/hip_runtime.h>
#include <hip/hip_bf16.h>

#define N_NODES 50000
#define N_EDGES 500000
#define N_FEAT 128
#define EMB_DIM 1024
#define HIDDEN 128
#define OUT_DIM 10
#define N_GRAPHS 64
#define NB_NODE 196   // ceil(N_NODES/256)

typedef __attribute__((ext_vector_type(8))) short short8;   // 8 bf16 = 4 VGPR (MFMA A/B frag)
typedef __attribute__((ext_vector_type(4))) float f32x4;    // MFMA C/D frag

// ---- fp32 -> bf16 RTN-even (finite inputs) ----
__device__ __forceinline__ unsigned short f2bf(float f) {
    unsigned int u = __float_as_uint(f);
    return (unsigned short)((u + 0x7fffu + ((u >> 16) & 1u)) >> 16);
}
// unpack a dword holding 2 bf16 (elements 2k, 2k+1); pack the inverse
__device__ __forceinline__ float bflo(unsigned int r) { return __uint_as_float(r << 16); }
__device__ __forceinline__ float bfhi(unsigned int r) { return __uint_as_float(r & 0xffff0000u); }
__device__ __forceinline__ unsigned int packbf(float lo, float hi) {
    return ((unsigned int)f2bf(hi) << 16) | f2bf(lo);
}

// ---------------- init: dc=0 (packed deg), zero pool buffers ----------------
__global__ __launch_bounds__(256) void k_init(unsigned long long* __restrict__ dc,
                                              float* __restrict__ sums,
                                              float* __restrict__ counts) {
    int i = blockIdx.x * 256 + threadIdx.x;
    if (i < N_NODES) dc[i] = 0ULL;
    if (i < N_GRAPHS * HIDDEN) sums[i] = 0.0f;
    if (i < N_GRAPHS) counts[i] = 0.0f;
}

// ------- degree scatter: ONE u64 atomic = (count<<32) | fixedpoint(ew, 2^24) --------
// ew in [0,1): fx < 2^24; max in-degree << 128 so low word never carries into count.
__global__ __launch_bounds__(256) void k_deg(const int* __restrict__ dst,
                                             const float* __restrict__ ew,
                                             unsigned long long* __restrict__ dc) {
    int e = blockIdx.x * 256 + threadIdx.x;
    if (e < N_EDGES) {
        unsigned int fx = (unsigned int)(ew[e] * 16777216.0f);
        atomicAdd(&dc[dst[e]], (1ULL << 32) | (unsigned long long)fx);
    }
}

// ---------------- scan pass 1: per-block (256 nodes) reduce of counts ----------------
__global__ __launch_bounds__(256) void k_scan1(const unsigned long long* __restrict__ dc,
                                               int* __restrict__ bsum) {
    __shared__ int wsum[4];
    int i = blockIdx.x * 256 + threadIdx.x;
    int v = (i < N_NODES) ? (int)((const uint2*)dc)[i].y : 0;
#pragma unroll
    for (int off = 32; off; off >>= 1) v += __shfl_down(v, off, 64);
    if ((threadIdx.x & 63) == 0) wsum[threadIdx.x >> 6] = v;
    __syncthreads();
    if (threadIdx.x == 0) bsum[blockIdx.x] = wsum[0] + wsum[1] + wsum[2] + wsum[3];
}

// ---------------- scan pass 2: exclusive scan of NB_NODE block sums (1 block) ------
__global__ __launch_bounds__(256) void k_scan2(int* __restrict__ bsum) {
    __shared__ int sh[256];
    int t = threadIdx.x;
    int v = (t < NB_NODE) ? bsum[t] : 0;
    sh[t] = v;
    __syncthreads();
    for (int off = 1; off < 256; off <<= 1) {
        int add = (t >= off) ? sh[t - off] : 0;
        __syncthreads();
        sh[t] += add;
        __syncthreads();
    }
    if (t < NB_NODE) bsum[t] = sh[t] - v;  // exclusive
}

// -------- scan pass 3: per-block exclusive scan + offset; dinv from packed dc -------
__global__ __launch_bounds__(256) void k_scan3(const unsigned long long* __restrict__ dc,
                                               const int* __restrict__ bofs,
                                               int* __restrict__ cursor,
                                               int* __restrict__ rowptr,
                                               float* __restrict__ dinv) {
    __shared__ int sh[256];
    const int t = threadIdx.x;
    const int i = blockIdx.x * 256 + t;
    uint2 d = (i < N_NODES) ? ((const uint2*)dc)[i] : make_uint2(0u, 0u);
    int v = (int)d.y;
    sh[t] = v;
    __syncthreads();
    for (int off = 1; off < 256; off <<= 1) {
        int add = (t >= off) ? sh[t - off] : 0;
        __syncthreads();
        sh[t] += add;
        __syncthreads();
    }
    int ex = sh[t] - v + bofs[blockIdx.x];
    if (i < N_NODES) {
        rowptr[i] = ex;
        cursor[i] = ex;
        float deg = 1.0f + (float)d.x * (1.0f / 16777216.0f);  // self loop + Σew
        dinv[i] = 1.0f / sqrtf(deg);
    }
    if (i == 0) rowptr[N_NODES] = N_EDGES;
}

// ---------------- fill CSR: csr[pos] = (src, norm) ----------------
__global__ __launch_bounds__(256) void k_fill(const int* __restrict__ src,
                                              const int* __restrict__ dst,
                                              const float* __restrict__ ew,
                                              const float* __restrict__ dinv,
                                              int* __restrict__ cursor,
                                              int2* __restrict__ csr) {
    int e = blockIdx.x * 256 + threadIdx.x;
    if (e >= N_EDGES) return;
    int s = src[e], d = dst[e];
    int pos = atomicAdd(&cursor[d], 1);
    float norm = dinv[s] * ew[e] * dinv[d];
    csr[pos] = make_int2(s, __float_as_int(norm));
}

// ---------------- W (K x 128) -> Wt (128 x K) bf16 (both W1, W2) ----------------
__device__ __forceinline__ void prep_one(const float* __restrict__ W,
                                         unsigned short* __restrict__ Wt,
                                         int K, int t) {
    int n = t & 127;
    int c = t >> 7;
    if (c * 16 >= K) return;
    short8 h0, h1;
#pragma unroll
    for (int i = 0; i < 16; i++) {
        unsigned short h = f2bf(W[(size_t)(c * 16 + i) * HIDDEN + n]);
        if (i < 8) h0[i] = (short)h;
        else       h1[i - 8] = (short)h;
    }
    size_t o = (size_t)n * K + c * 16;
    *(short8*)&Wt[o] = h0;
    *(short8*)&Wt[o + 8] = h1;
}

__global__ __launch_bounds__(256) void k_prep(const float* __restrict__ W1,
                                              unsigned short* __restrict__ Wt1,
                                              const float* __restrict__ W2,
                                              unsigned short* __restrict__ Wt2) {
    int b = blockIdx.x;
    if (b < 36) prep_one(W1, Wt1, N_FEAT + EMB_DIM, b * 256 + threadIdx.x);
    else        prep_one(W2, Wt2, HIDDEN, (b - 36) * 256 + threadIdx.x);
}

// ---------------- bf16 MFMA GEMM: tbf[M,128] = A[M,K] @ W[K,128], bf16 out ----------
// Block: 128x128, 256 threads (4 waves 2x2), 64x64 per wave, BK=32, fp32 accum.
// MODE 0: A row m = [ x[m,0:128] | emb[ids[m],0:1024] ]  (K=1152, fp32 -> bf16)
// MODE 1: A row m = Xb[m,0:128] (already-relu'd bf16, straight copy)  (K=128)
template <int MODE>
__global__ __launch_bounds__(256) void k_gemm(const float* __restrict__ X,
                                              const unsigned short* __restrict__ Xb,
                                              const float* __restrict__ EMB,
                                              const int* __restrict__ ids,
                                              const unsigned short* __restrict__ Wt,
                                              unsigned short* __restrict__ tbf, int K) {
    __shared__ unsigned short As[128][40];  // [row][k], stride 40 (80 B, 16B-aligned)
    __shared__ unsigned short Bs[128][40];  // [col][k]

    const int tid = threadIdx.x;
    const int lane = tid & 63;
    const int wv = tid >> 6;
    const int wm = wv >> 1, wn = wv & 1;     // wave quadrant
    const int fr = lane & 15;                // frag row/col
    const int fq = lane >> 4;                // frag k-octet
    const int mBase = blockIdx.x * 128;

    const int aRow = tid >> 1;
    const int aOff = (tid & 1) * 16;
    const int m = mBase + aRow;
    const int mc = (m < N_NODES) ? m : (N_NODES - 1);
    int embRow = 0;
    if (MODE == 0) embRow = ids[mc];

    f32x4 acc[4][4];
#pragma unroll
    for (int i = 0; i < 4; i++)
#pragma unroll
        for (int j = 0; j < 4; j++) acc[i][j] = (f32x4){0.f, 0.f, 0.f, 0.f};

    // prefetch k0=0 globals
    float av[16];
    short8 axb0, axb1;
    short8 bh0, bh1;
    {
        if (MODE == 0) {
            const float* aptr = X + (size_t)mc * N_FEAT + aOff;
            *(float4*)&av[0]  = *(const float4*)(aptr);
            *(float4*)&av[4]  = *(const float4*)(aptr + 4);
            *(float4*)&av[8]  = *(const float4*)(aptr + 8);
            *(float4*)&av[12] = *(const float4*)(aptr + 12);
        } else {
            const unsigned short* aptr = Xb + (size_t)mc * HIDDEN + aOff;
            axb0 = *(const short8*)(aptr);
            axb1 = *(const short8*)(aptr + 8);
        }
        size_t bo = (size_t)aRow * K + aOff;
        bh0 = *(const short8*)&Wt[bo];
        bh1 = *(const short8*)&Wt[bo + 8];
    }

    for (int k0 = 0; k0 < K; k0 += 32) {
        short8 ah0, ah1;
        if (MODE == 0) {
#pragma unroll
            for (int i = 0; i < 16; i++) {
                unsigned short h = f2bf(av[i]);
                if (i < 8) ah0[i] = (short)h;
                else       ah1[i - 8] = (short)h;
            }
        } else {
            ah0 = axb0; ah1 = axb1;
        }
        *(short8*)&As[aRow][aOff] = ah0; *(short8*)&As[aRow][aOff + 8] = ah1;
        *(short8*)&Bs[aRow][aOff] = bh0; *(short8*)&Bs[aRow][aOff + 8] = bh1;
        __syncthreads();

        // prefetch next k-step globals (hidden behind MFMAs)
        int k1 = k0 + 32;
        if (k1 < K) {
            if (MODE == 0) {
                const float* aptr = (k1 < N_FEAT)
                    ? X + (size_t)mc * N_FEAT + k1 + aOff
                    : EMB + (size_t)embRow * EMB_DIM + (k1 - N_FEAT) + aOff;
                *(float4*)&av[0]  = *(const float4*)(aptr);
                *(float4*)&av[4]  = *(const float4*)(aptr + 4);
                *(float4*)&av[8]  = *(const float4*)(aptr + 8);
                *(float4*)&av[12] = *(const float4*)(aptr + 12);
            } else {
                const unsigned short* aptr = Xb + (size_t)mc * HIDDEN + k1 + aOff;
                axb0 = *(const short8*)(aptr);
                axb1 = *(const short8*)(aptr + 8);
            }
            size_t bo = (size_t)aRow * K + k1 + aOff;
            bh0 = *(const short8*)&Wt[bo];
            bh1 = *(const short8*)&Wt[bo + 8];
        }

        short8 aF[4], bF[4];
#pragma unroll
        for (int i = 0; i < 4; i++) {
            aF[i] = *(const short8*)&As[wm * 64 + i * 16 + fr][fq * 8];
            bF[i] = *(const short8*)&Bs[wn * 64 + i * 16 + fr][fq * 8];
        }

#pragma unroll
        for (int i = 0; i < 4; i++)
#pragma unroll
            for (int j = 0; j < 4; j++)
                acc[i][j] = __builtin_amdgcn_mfma_f32_16x16x32_bf16(aF[i], bF[j], acc[i][j], 0, 0, 0);
        __syncthreads();
    }

    // epilogue: C/D map col=lane&15, row=(lane>>4)*4+reg ; write bf16
#pragma unroll
    for (int i = 0; i < 4; i++) {
#pragma unroll
        for (int j = 0; j < 4; j++) {
            int gcol = wn * 64 + j * 16 + fr;
#pragma unroll
            for (int r = 0; r < 4; r++) {
                int grow = mBase + wm * 64 + i * 16 + fq * 4 + r;
                if (grow < N_NODES) tbf[(size_t)grow * HIDDEN + gcol] = f2bf(acc[i][j][r]);
            }
        }
    }
}

// ---------------- CSR gather-aggregate, wave/node, 16 lanes per edge-row ------------
// 4 edges per wave-step, uint4 (16B) per lane; groups reduced by shfl_xor butterfly.
// acc[n,:] = sum_e norm_e * t[src_e,:] + dinv[n]^2 * t[n,:] + b ; then relu.
// POOL=0: write bf16 row (= h1, feeds gemm1).  POOL=1: per-block LDS pool.
template <int POOL, int NWAVE>
__global__ __launch_bounds__(NWAVE * 64) void k_agg(const int2* __restrict__ csr,
                                                    const int* __restrict__ rowptr,
                                                    const float* __restrict__ dinv,
                                                    const unsigned short* __restrict__ tbf,
                                                    const float* __restrict__ bias,
                                                    const int* __restrict__ batch,
                                                    unsigned short* __restrict__ outb,
                                                    float* __restrict__ sums,
                                                    float* __restrict__ counts) {
    __shared__ float lsum[HIDDEN];
    __shared__ int lcnt;
    const int wv = threadIdx.x >> 6;
    const int lane = threadIdx.x & 63;
    const int grp = lane >> 4;       // edge slot within 4-group
    const int q = lane & 15;         // column quad: cols q*8 .. q*8+7
    const int n = blockIdx.x * NWAVE + wv;
    const uint4* t128 = (const uint4*)tbf;   // row n = 16 uint4 at n*16

    if (POOL) {
        if (threadIdx.x < HIDDEN) lsum[threadIdx.x] = 0.f;
        if (threadIdx.x == 0) lcnt = 0;
        __syncthreads();
    }

    float acc[8] = {};
    if (n < N_NODES) {
        const int beg = rowptr[n];
        const int end = rowptr[n + 1];
        const float di = dinv[n];
        const float wself = (grp == 0) ? di * di : 0.f;
        uint4 sr = t128[(size_t)n * 16 + q];
        acc[0] = wself * bflo(sr.x); acc[1] = wself * bfhi(sr.x);
        acc[2] = wself * bflo(sr.y); acc[3] = wself * bfhi(sr.y);
        acc[4] = wself * bflo(sr.z); acc[5] = wself * bfhi(sr.z);
        acc[6] = wself * bflo(sr.w); acc[7] = wself * bfhi(sr.w);
        if (grp == 0) {
            float4 b0 = ((const float4*)bias)[q * 2];
            float4 b1 = ((const float4*)bias)[q * 2 + 1];
            acc[0] += b0.x; acc[1] += b0.y; acc[2] += b0.z; acc[3] += b0.w;
            acc[4] += b1.x; acc[5] += b1.y; acc[6] += b1.z; acc[7] += b1.w;
        }

        for (int base = beg; base < end; base += 64) {
            int cnt = end - base; if (cnt > 64) cnt = 64;
            int2 ce = (lane < cnt) ? csr[base + lane] : make_int2(0, 0);
            int j = 0;
            for (; j + 8 <= cnt; j += 8) {       // 8 edges: 2 uint4 gathers in flight
                int   sA = __shfl(ce.x, j + grp);
                float wA = __int_as_float(__shfl(ce.y, j + grp));
                int   sB = __shfl(ce.x, j + 4 + grp);
                float wB = __int_as_float(__shfl(ce.y, j + 4 + grp));
                uint4 rA = t128[(size_t)sA * 16 + q];
                uint4 rB = t128[(size_t)sB * 16 + q];
                acc[0] = fmaf(wA, bflo(rA.x), acc[0]); acc[1] = fmaf(wA, bfhi(rA.x), acc[1]);
                acc[2] = fmaf(wA, bflo(rA.y), acc[2]); acc[3] = fmaf(wA, bfhi(rA.y), acc[3]);
                acc[4] = fmaf(wA, bflo(rA.z), acc[4]); acc[5] = fmaf(wA, bfhi(rA.z), acc[5]);
                acc[6] = fmaf(wA, bflo(rA.w), acc[6]); acc[7] = fmaf(wA, bfhi(rA.w), acc[7]);
                acc[0] = fmaf(wB, bflo(rB.x), acc[0]); acc[1] = fmaf(wB, bfhi(rB.x), acc[1]);
                acc[2] = fmaf(wB, bflo(rB.y), acc[2]); acc[3] = fmaf(wB, bfhi(rB.y), acc[3]);
                acc[4] = fmaf(wB, bflo(rB.z), acc[4]); acc[5] = fmaf(wB, bfhi(rB.z), acc[5]);
                acc[6] = fmaf(wB, bflo(rB.w), acc[6]); acc[7] = fmaf(wB, bfhi(rB.w), acc[7]);
            }
            for (; j < cnt; j += 4) {            // tail groups (w=0 pads beyond cnt)
                int   s = __shfl(ce.x, j + grp);
                float w = __int_as_float(__shfl(ce.y, j + grp));
                uint4 r = t128[(size_t)s * 16 + q];
                acc[0] = fmaf(w, bflo(r.x), acc[0]); acc[1] = fmaf(w, bfhi(r.x), acc[1]);
                acc[2] = fmaf(w, bflo(r.y), acc[2]); acc[3] = fmaf(w, bfhi(r.y), acc[3]);
                acc[4] = fmaf(w, bflo(r.z), acc[4]); acc[5] = fmaf(w, bfhi(r.z), acc[5]);
                acc[6] = fmaf(w, bflo(r.w), acc[6]); acc[7] = fmaf(w, bfhi(r.w), acc[7]);
            }
        }
    }

    // reduce the 4 edge-groups: lanes l, l^16, l^32, l^48 hold same columns
#pragma unroll
    for (int i = 0; i < 8; i++) {
        acc[i] += __shfl_xor(acc[i], 16);
        acc[i] += __shfl_xor(acc[i], 32);
    }

    if (!POOL) {
        if (n < N_NODES && grp == 0) {
#pragma unroll
            for (int i = 0; i < 8; i++) acc[i] = fmaxf(acc[i], 0.f);  // relu (h1)
            uint4 o;
            o.x = packbf(acc[0], acc[1]);
            o.y = packbf(acc[2], acc[3]);
            o.z = packbf(acc[4], acc[5]);
            o.w = packbf(acc[6], acc[7]);
            ((uint4*)outb)[(size_t)n * 16 + q] = o;
        }
    } else {
        if (n < N_NODES && grp == 0) {
#pragma unroll
            for (int i = 0; i < 8; i++) acc[i] = fmaxf(acc[i], 0.f);  // relu
            int g = batch[n];
            int g0 = batch[blockIdx.x * NWAVE];
            if (g == g0) {
#pragma unroll
                for (int i = 0; i < 8; i++) atomicAdd(&lsum[q * 8 + i], acc[i]);
                if (lane == 0) atomicAdd(&lcnt, 1);
            } else {  // rare boundary node: direct global
#pragma unroll
                for (int i = 0; i < 8; i++) atomicAdd(&sums[g * HIDDEN + q * 8 + i], acc[i]);
                if (lane == 0) atomicAdd(&counts[g], 1.0f);
            }
        }
        __syncthreads();
        int g0 = batch[blockIdx.x * NWAVE];
        if (threadIdx.x < HIDDEN) atomicAdd(&sums[g0 * HIDDEN + threadIdx.x], lsum[threadIdx.x]);
        if (threadIdx.x == 0) atomicAdd(&counts[g0], (float)lcnt);
    }
}

// ---------------- final: out[g,o] = (sums[g,:]/max(cnt,1)) @ fcW + fcb -------------
__global__ __launch_bounds__(64) void k_final(const float* __restrict__ sums,
                                              const float* __restrict__ counts,
                                              const float* __restrict__ fcW,
                                              const float* __restrict__ fcb,
                                              float* __restrict__ out) {
    int g = blockIdx.x;
    int o = threadIdx.x;
    if (o >= OUT_DIM) return;
    float inv = 1.0f / fmaxf(counts[g], 1.0f);
    float acc = 0.f;
    for (int f = 0; f < HIDDEN; f++)
        acc = fmaf(sums[g * HIDDEN + f], fcW[f * OUT_DIM + o], acc);
    out[g * OUT_DIM + o] = acc * inv + fcb[o];
}

extern "C" void kernel_launch(void* const* d_in, const int* in_sizes, int n_in,
                              void* d_out, int out_size, void* d_ws, size_t ws_size,
                              hipStream_t stream) {
    const float* x      = (const float*)d_in[0];
    const float* ew     = (const float*)d_in[1];
    const float* emb    = (const float*)d_in[2];
    const float* W1     = (const float*)d_in[3];
    const float* b1     = (const float*)d_in[4];
    const float* W2     = (const float*)d_in[5];
    const float* b2     = (const float*)d_in[6];
    const float* fcW    = (const float*)d_in[7];
    const float* fcb    = (const float*)d_in[8];
    const int* edge_idx = (const int*)d_in[9];
    const int* batch    = (const int*)d_in[10];
    const int* node_ids = (const int*)d_in[11];
    float* out = (float*)d_out;

    const int* src = edge_idx;             // edge_index[0]
    const int* dst = edge_idx + N_EDGES;   // edge_index[1]

    // workspace layout (float units; bf16 buffers 16B-aligned)
    float* ws     = (float*)d_ws;
    float* dinv   = ws;                                        // 50048
    unsigned long long* dc = (unsigned long long*)(ws + 50048);// 50000 u64 = 100000 f
    int*   cursor = (int*)(ws + 150048);                       // 50048
    int*   rowptr = (int*)(ws + 200096);                       // 50056
    int*   bsum   = (int*)(ws + 250152);                       // 256
    int2*  csr    = (int2*)(ws + 250408);                      // 500000 int2 = 1M f
    unsigned short* tbf   = (unsigned short*)(ws + 1250408);   // 6.4M bf16 = 3.2M f
    unsigned short* out1b = (unsigned short*)(ws + 4450408);   // 6.4M bf16 (h1)
    float* sums   = ws + 7650408;                              // 8192
    float* counts = sums + N_GRAPHS * HIDDEN;                  // 64
    unsigned short* wt1 = (unsigned short*)(ws + 7658664);     // 147456 bf16
    unsigned short* wt2 = (unsigned short*)(ws + 7732392);     // 16384 bf16
    // end ~7740584 floats = 31 MB

    const int NB_EDGE = (N_EDGES + 255) / 256;           // 1954
    const int NB_GEMM = (N_NODES + 127) / 128;           // 391
    const int K1 = N_FEAT + EMB_DIM;                     // 1152

    // preprocessing: packed degrees, multi-block scan, CSR, weights
    k_init <<<NB_NODE, 256, 0, stream>>>(dc, sums, counts);
    k_deg  <<<NB_EDGE, 256, 0, stream>>>(dst, ew, dc);
    k_scan1<<<NB_NODE, 256, 0, stream>>>(dc, bsum);
    k_scan2<<<1, 256, 0, stream>>>(bsum);
    k_scan3<<<NB_NODE, 256, 0, stream>>>(dc, bsum, cursor, rowptr, dinv);
    k_fill <<<NB_EDGE, 256, 0, stream>>>(src, dst, ew, dinv, cursor, csr);
    k_prep <<<40, 256, 0, stream>>>(W1, wt1, W2, wt2);

    // conv1: t1 = [x|emb] @ W1 (bf16) ; h1 = relu(aggregate + self + b1) (bf16)
    k_gemm<0><<<NB_GEMM, 256, 0, stream>>>(x, nullptr, emb, node_ids, wt1, tbf, K1);
    k_agg<0, 4><<<(N_NODES + 3) / 4, 256, 0, stream>>>(csr, rowptr, dinv, tbf, b1,
                                                       batch, out1b, sums, counts);

    // conv2: t2 = h1 @ W2 (bf16) ; fused aggregate+relu+pool
    k_gemm<1><<<NB_GEMM, 256, 0, stream>>>(nullptr, out1b, nullptr, nullptr, wt2, tbf, HIDDEN);
    k_agg<1, 16><<<(N_NODES + 15) / 16, 1024, 0, stream>>>(csr, rowptr, dinv, tbf, b2,
                                                           batch, nullptr, sums, counts);

    // classifier
    k_final<<<N_GRAPHS, 64, 0, stream>>>(sums, counts, fcW, fcb, out);
}

// Round 3
// 508.090 us; speedup vs baseline: 1.0461x; 1.0461x over previous
//
#include <hip/hip_runtime.h>
#include <hip/hip_bf16.h>

#define N_NODES 50000
#define N_EDGES 500000
#define N_FEAT 128
#define EMB_DIM 1024
#define HIDDEN 128
#define OUT_DIM 10
#define N_GRAPHS 64
#define NB_NODE 196   // ceil(N_NODES/256)

typedef __attribute__((ext_vector_type(8))) short short8;   // 8 bf16 = 4 VGPR (MFMA A/B frag)
typedef __attribute__((ext_vector_type(4))) float f32x4;    // MFMA C/D frag

// ---- fp32 -> bf16 RTN-even (finite inputs) ----
__device__ __forceinline__ unsigned short f2bf(float f) {
    unsigned int u = __float_as_uint(f);
    return (unsigned short)((u + 0x7fffu + ((u >> 16) & 1u)) >> 16);
}
// unpack a dword holding 2 bf16 (elements 2k, 2k+1); pack the inverse
__device__ __forceinline__ float bflo(unsigned int r) { return __uint_as_float(r << 16); }
__device__ __forceinline__ float bfhi(unsigned int r) { return __uint_as_float(r & 0xffff0000u); }
__device__ __forceinline__ unsigned int packbf(float lo, float hi) {
    return ((unsigned int)f2bf(hi) << 16) | f2bf(lo);
}

// ---------------- init: dc=0 (packed deg), zero pool buffers ----------------
__global__ __launch_bounds__(256) void k_init(unsigned long long* __restrict__ dc,
                                              float* __restrict__ sums,
                                              float* __restrict__ counts) {
    int i = blockIdx.x * 256 + threadIdx.x;
    if (i < N_NODES) dc[i] = 0ULL;
    if (i < N_GRAPHS * HIDDEN) sums[i] = 0.0f;
    if (i < N_GRAPHS) counts[i] = 0.0f;
}

// ------- degree scatter: ONE u64 atomic = (count<<32) | fixedpoint(ew, 2^24) --------
// ew in [0,1): fx < 2^24; max in-degree << 128 so low word never carries into count.
__global__ __launch_bounds__(256) void k_deg(const int* __restrict__ dst,
                                             const float* __restrict__ ew,
                                             unsigned long long* __restrict__ dc) {
    int e = blockIdx.x * 256 + threadIdx.x;
    if (e < N_EDGES) {
        unsigned int fx = (unsigned int)(ew[e] * 16777216.0f);
        atomicAdd(&dc[dst[e]], (1ULL << 32) | (unsigned long long)fx);
    }
}

// ---------------- scan pass 1: per-block (256 nodes) reduce of counts ----------------
__global__ __launch_bounds__(256) void k_scan1(const unsigned long long* __restrict__ dc,
                                               int* __restrict__ bsum) {
    __shared__ int wsum[4];
    int i = blockIdx.x * 256 + threadIdx.x;
    int v = (i < N_NODES) ? (int)((const uint2*)dc)[i].y : 0;
#pragma unroll
    for (int off = 32; off; off >>= 1) v += __shfl_down(v, off, 64);
    if ((threadIdx.x & 63) == 0) wsum[threadIdx.x >> 6] = v;
    __syncthreads();
    if (threadIdx.x == 0) bsum[blockIdx.x] = wsum[0] + wsum[1] + wsum[2] + wsum[3];
}

// ---------------- scan pass 2: exclusive scan of NB_NODE block sums (1 block) ------
__global__ __launch_bounds__(256) void k_scan2(int* __restrict__ bsum) {
    __shared__ int sh[256];
    int t = threadIdx.x;
    int v = (t < NB_NODE) ? bsum[t] : 0;
    sh[t] = v;
    __syncthreads();
    for (int off = 1; off < 256; off <<= 1) {
        int add = (t >= off) ? sh[t - off] : 0;
        __syncthreads();
        sh[t] += add;
        __syncthreads();
    }
    if (t < NB_NODE) bsum[t] = sh[t] - v;  // exclusive
}

// -------- scan pass 3: per-block exclusive scan + offset; dinv from packed dc -------
__global__ __launch_bounds__(256) void k_scan3(const unsigned long long* __restrict__ dc,
                                               const int* __restrict__ bofs,
                                               int* __restrict__ cursor,
                                               int* __restrict__ rowptr,
                                               float* __restrict__ dinv) {
    __shared__ int sh[256];
    const int t = threadIdx.x;
    const int i = blockIdx.x * 256 + t;
    uint2 d = (i < N_NODES) ? ((const uint2*)dc)[i] : make_uint2(0u, 0u);
    int v = (int)d.y;
    sh[t] = v;
    __syncthreads();
    for (int off = 1; off < 256; off <<= 1) {
        int add = (t >= off) ? sh[t - off] : 0;
        __syncthreads();
        sh[t] += add;
        __syncthreads();
    }
    int ex = sh[t] - v + bofs[blockIdx.x];
    if (i < N_NODES) {
        rowptr[i] = ex;
        cursor[i] = ex;
        float deg = 1.0f + (float)d.x * (1.0f / 16777216.0f);  // self loop + Σew
        dinv[i] = 1.0f / sqrtf(deg);
    }
    if (i == 0) rowptr[N_NODES] = N_EDGES;
}

// ---------------- fill CSR: csr[pos] = (src, norm) ----------------
__global__ __launch_bounds__(256) void k_fill(const int* __restrict__ src,
                                              const int* __restrict__ dst,
                                              const float* __restrict__ ew,
                                              const float* __restrict__ dinv,
                                              int* __restrict__ cursor,
                                              int2* __restrict__ csr) {
    int e = blockIdx.x * 256 + threadIdx.x;
    if (e >= N_EDGES) return;
    int s = src[e], d = dst[e];
    int pos = atomicAdd(&cursor[d], 1);
    float norm = dinv[s] * ew[e] * dinv[d];
    csr[pos] = make_int2(s, __float_as_int(norm));
}

// ---------------- W (K x 128) -> Wt (128 x K) bf16 (both W1, W2) ----------------
__device__ __forceinline__ void prep_one(const float* __restrict__ W,
                                         unsigned short* __restrict__ Wt,
                                         int K, int t) {
    int n = t & 127;
    int c = t >> 7;
    if (c * 16 >= K) return;
    short8 h0, h1;
#pragma unroll
    for (int i = 0; i < 16; i++) {
        unsigned short h = f2bf(W[(size_t)(c * 16 + i) * HIDDEN + n]);
        if (i < 8) h0[i] = (short)h;
        else       h1[i - 8] = (short)h;
    }
    size_t o = (size_t)n * K + c * 16;
    *(short8*)&Wt[o] = h0;
    *(short8*)&Wt[o + 8] = h1;
}

__global__ __launch_bounds__(256) void k_prep(const float* __restrict__ W1,
                                              unsigned short* __restrict__ Wt1,
                                              const float* __restrict__ W2,
                                              unsigned short* __restrict__ Wt2) {
    int b = blockIdx.x;
    if (b < 36) prep_one(W1, Wt1, N_FEAT + EMB_DIM, b * 256 + threadIdx.x);
    else        prep_one(W2, Wt2, HIDDEN, (b - 36) * 256 + threadIdx.x);
}

// ---------------- bf16 MFMA GEMM: tbf[M,128] = A[M,K] @ W[K,128], bf16 out ----------
// Block: 128x128, 256 threads (4 waves 2x2), 64x64 per wave, BK=32, fp32 accum.
// MODE 0: A row m = [ x[m,0:128] | emb[ids[m],0:1024] ]  (K=1152, fp32 -> bf16)
// MODE 1: A row m = Xb[m,0:128] (already-relu'd bf16, straight copy)  (K=128)
template <int MODE>
__global__ __launch_bounds__(256) void k_gemm(const float* __restrict__ X,
                                              const unsigned short* __restrict__ Xb,
                                              const float* __restrict__ EMB,
                                              const int* __restrict__ ids,
                                              const unsigned short* __restrict__ Wt,
                                              unsigned short* __restrict__ tbf, int K) {
    __shared__ unsigned short As[128][40];  // [row][k], stride 40 (80 B, 16B-aligned)
    __shared__ unsigned short Bs[128][40];  // [col][k]

    const int tid = threadIdx.x;
    const int lane = tid & 63;
    const int wv = tid >> 6;
    const int wm = wv >> 1, wn = wv & 1;     // wave quadrant
    const int fr = lane & 15;                // frag row/col
    const int fq = lane >> 4;                // frag k-octet
    const int mBase = blockIdx.x * 128;

    const int aRow = tid >> 1;
    const int aOff = (tid & 1) * 16;
    const int m = mBase + aRow;
    const int mc = (m < N_NODES) ? m : (N_NODES - 1);
    int embRow = 0;
    if (MODE == 0) embRow = ids[mc];

    f32x4 acc[4][4];
#pragma unroll
    for (int i = 0; i < 4; i++)
#pragma unroll
        for (int j = 0; j < 4; j++) acc[i][j] = (f32x4){0.f, 0.f, 0.f, 0.f};

    // prefetch k0=0 globals
    float av[16];
    short8 axb0, axb1;
    short8 bh0, bh1;
    {
        if (MODE == 0) {
            const float* aptr = X + (size_t)mc * N_FEAT + aOff;
            *(float4*)&av[0]  = *(const float4*)(aptr);
            *(float4*)&av[4]  = *(const float4*)(aptr + 4);
            *(float4*)&av[8]  = *(const float4*)(aptr + 8);
            *(float4*)&av[12] = *(const float4*)(aptr + 12);
        } else {
            const unsigned short* aptr = Xb + (size_t)mc * HIDDEN + aOff;
            axb0 = *(const short8*)(aptr);
            axb1 = *(const short8*)(aptr + 8);
        }
        size_t bo = (size_t)aRow * K + aOff;
        bh0 = *(const short8*)&Wt[bo];
        bh1 = *(const short8*)&Wt[bo + 8];
    }

    for (int k0 = 0; k0 < K; k0 += 32) {
        short8 ah0, ah1;
        if (MODE == 0) {
#pragma unroll
            for (int i = 0; i < 16; i++) {
                unsigned short h = f2bf(av[i]);
                if (i < 8) ah0[i] = (short)h;
                else       ah1[i - 8] = (short)h;
            }
        } else {
            ah0 = axb0; ah1 = axb1;
        }
        *(short8*)&As[aRow][aOff] = ah0; *(short8*)&As[aRow][aOff + 8] = ah1;
        *(short8*)&Bs[aRow][aOff] = bh0; *(short8*)&Bs[aRow][aOff + 8] = bh1;
        __syncthreads();

        // prefetch next k-step globals (hidden behind MFMAs)
        int k1 = k0 + 32;
        if (k1 < K) {
            if (MODE == 0) {
                const float* aptr = (k1 < N_FEAT)
                    ? X + (size_t)mc * N_FEAT + k1 + aOff
                    : EMB + (size_t)embRow * EMB_DIM + (k1 - N_FEAT) + aOff;
                *(float4*)&av[0]  = *(const float4*)(aptr);
                *(float4*)&av[4]  = *(const float4*)(aptr + 4);
                *(float4*)&av[8]  = *(const float4*)(aptr + 8);
                *(float4*)&av[12] = *(const float4*)(aptr + 12);
            } else {
                const unsigned short* aptr = Xb + (size_t)mc * HIDDEN + k1 + aOff;
                axb0 = *(const short8*)(aptr);
                axb1 = *(const short8*)(aptr + 8);
            }
            size_t bo = (size_t)aRow * K + k1 + aOff;
            bh0 = *(const short8*)&Wt[bo];
            bh1 = *(const short8*)&Wt[bo + 8];
        }

        short8 aF[4], bF[4];
#pragma unroll
        for (int i = 0; i < 4; i++) {
            aF[i] = *(const short8*)&As[wm * 64 + i * 16 + fr][fq * 8];
            bF[i] = *(const short8*)&Bs[wn * 64 + i * 16 + fr][fq * 8];
        }

#pragma unroll
        for (int i = 0; i < 4; i++)
#pragma unroll
            for (int j = 0; j < 4; j++)
                acc[i][j] = __builtin_amdgcn_mfma_f32_16x16x32_bf16(aF[i], bF[j], acc[i][j], 0, 0, 0);
        __syncthreads();
    }

    // epilogue: C/D map col=lane&15, row=(lane>>4)*4+reg ; write bf16
#pragma unroll
    for (int i = 0; i < 4; i++) {
#pragma unroll
        for (int j = 0; j < 4; j++) {
            int gcol = wn * 64 + j * 16 + fr;
#pragma unroll
            for (int r = 0; r < 4; r++) {
                int grow = mBase + wm * 64 + i * 16 + fq * 4 + r;
                if (grow < N_NODES) tbf[(size_t)grow * HIDDEN + gcol] = f2bf(acc[i][j][r]);
            }
        }
    }
}

// ---------------- CSR gather-aggregate: 16 lanes per NODE, 4 nodes per wave ---------
// Each 16-lane group owns one node; per lane: 8 columns (q*8..q*8+7, 16B/row).
// Edge loop pipelines 4 independent row-gathers (r0..r3) per iteration; pad edges
// alias the node's own (L1-hot) row with weight 0 so the loop body is uniform.
// acc[n,:] = sum_e norm_e * t[src_e,:] + dinv[n]^2 * t[n,:] + b ; then relu.
// POOL=0: write bf16 row (= h1, feeds gemm1).  POOL=1: per-block LDS pool.
template <int POOL, int NWAVE>
__global__ __launch_bounds__(NWAVE * 64) void k_agg(const int2* __restrict__ csr,
                                                    const int* __restrict__ rowptr,
                                                    const float* __restrict__ dinv,
                                                    const unsigned short* __restrict__ tbf,
                                                    const float* __restrict__ bias,
                                                    const int* __restrict__ batch,
                                                    unsigned short* __restrict__ outb,
                                                    float* __restrict__ sums,
                                                    float* __restrict__ counts) {
    __shared__ float lsum[HIDDEN];
    __shared__ int lcnt;
    const int wv = threadIdx.x >> 6;
    const int lane = threadIdx.x & 63;
    const int grp = lane >> 4;       // node slot within wave
    const int q = lane & 15;         // column quad: cols q*8 .. q*8+7
    const int gl = grp << 4;         // first lane of this group
    const int n = (blockIdx.x * NWAVE + wv) * 4 + grp;
    const uint4* t128 = (const uint4*)tbf;   // row n = 16 uint4 at n*16

    if (POOL) {
        if (threadIdx.x < HIDDEN) lsum[threadIdx.x] = 0.f;
        if (threadIdx.x == 0) lcnt = 0;
        __syncthreads();
    }

    float acc[8] = {};
    if (n < N_NODES) {
        const int beg = rowptr[n];
        const int end = rowptr[n + 1];
        const float di = dinv[n];
        const float wself = di * di;
        uint4 sr = t128[(size_t)n * 16 + q];
        float4 b0 = ((const float4*)bias)[q * 2];
        float4 b1 = ((const float4*)bias)[q * 2 + 1];
        acc[0] = fmaf(wself, bflo(sr.x), b0.x); acc[1] = fmaf(wself, bfhi(sr.x), b0.y);
        acc[2] = fmaf(wself, bflo(sr.y), b0.z); acc[3] = fmaf(wself, bfhi(sr.y), b0.w);
        acc[4] = fmaf(wself, bflo(sr.z), b1.x); acc[5] = fmaf(wself, bfhi(sr.z), b1.y);
        acc[6] = fmaf(wself, bflo(sr.w), b1.z); acc[7] = fmaf(wself, bfhi(sr.w), b1.w);

        for (int base = beg; base < end; base += 16) {
            int cnt = end - base; if (cnt > 16) cnt = 16;
            // lane q holds edge base+q of THIS group's node; pads: own row, w=0
            int2 ce = (q < cnt) ? csr[base + q] : make_int2(n, 0);
            for (int j = 0; j < cnt; j += 4) {   // last iter may use pads (w=0)
                int   s0 = __shfl(ce.x, gl + j);
                float w0 = __int_as_float(__shfl(ce.y, gl + j));
                int   s1 = __shfl(ce.x, gl + j + 1);
                float w1 = __int_as_float(__shfl(ce.y, gl + j + 1));
                int   s2 = __shfl(ce.x, gl + j + 2);
                float w2 = __int_as_float(__shfl(ce.y, gl + j + 2));
                int   s3 = __shfl(ce.x, gl + j + 3);
                float w3 = __int_as_float(__shfl(ce.y, gl + j + 3));
                uint4 r0 = t128[(size_t)s0 * 16 + q];   // 4 independent gathers
                uint4 r1 = t128[(size_t)s1 * 16 + q];   // in flight together
                uint4 r2 = t128[(size_t)s2 * 16 + q];
                uint4 r3 = t128[(size_t)s3 * 16 + q];
                acc[0] = fmaf(w0, bflo(r0.x), acc[0]); acc[1] = fmaf(w0, bfhi(r0.x), acc[1]);
                acc[2] = fmaf(w0, bflo(r0.y), acc[2]); acc[3] = fmaf(w0, bfhi(r0.y), acc[3]);
                acc[4] = fmaf(w0, bflo(r0.z), acc[4]); acc[5] = fmaf(w0, bfhi(r0.z), acc[5]);
                acc[6] = fmaf(w0, bflo(r0.w), acc[6]); acc[7] = fmaf(w0, bfhi(r0.w), acc[7]);
                acc[0] = fmaf(w1, bflo(r1.x), acc[0]); acc[1] = fmaf(w1, bfhi(r1.x), acc[1]);
                acc[2] = fmaf(w1, bflo(r1.y), acc[2]); acc[3] = fmaf(w1, bfhi(r1.y), acc[3]);
                acc[4] = fmaf(w1, bflo(r1.z), acc[4]); acc[5] = fmaf(w1, bfhi(r1.z), acc[5]);
                acc[6] = fmaf(w1, bflo(r1.w), acc[6]); acc[7] = fmaf(w1, bfhi(r1.w), acc[7]);
                acc[0] = fmaf(w2, bflo(r2.x), acc[0]); acc[1] = fmaf(w2, bfhi(r2.x), acc[1]);
                acc[2] = fmaf(w2, bflo(r2.y), acc[2]); acc[3] = fmaf(w2, bfhi(r2.y), acc[3]);
                acc[4] = fmaf(w2, bflo(r2.z), acc[4]); acc[5] = fmaf(w2, bfhi(r2.z), acc[5]);
                acc[6] = fmaf(w2, bflo(r2.w), acc[6]); acc[7] = fmaf(w2, bfhi(r2.w), acc[7]);
                acc[0] = fmaf(w3, bflo(r3.x), acc[0]); acc[1] = fmaf(w3, bfhi(r3.x), acc[1]);
                acc[2] = fmaf(w3, bflo(r3.y), acc[2]); acc[3] = fmaf(w3, bfhi(r3.y), acc[3]);
                acc[4] = fmaf(w3, bflo(r3.z), acc[4]); acc[5] = fmaf(w3, bfhi(r3.z), acc[5]);
                acc[6] = fmaf(w3, bflo(r3.w), acc[6]); acc[7] = fmaf(w3, bfhi(r3.w), acc[7]);
            }
        }
    }

    if (!POOL) {
        if (n < N_NODES) {
#pragma unroll
            for (int i = 0; i < 8; i++) acc[i] = fmaxf(acc[i], 0.f);  // relu (h1)
            uint4 o;
            o.x = packbf(acc[0], acc[1]);
            o.y = packbf(acc[2], acc[3]);
            o.z = packbf(acc[4], acc[5]);
            o.w = packbf(acc[6], acc[7]);
            ((uint4*)outb)[(size_t)n * 16 + q] = o;
        }
    } else {
        if (n < N_NODES) {
#pragma unroll
            for (int i = 0; i < 8; i++) acc[i] = fmaxf(acc[i], 0.f);  // relu
            int g = batch[n];
            int g0 = batch[blockIdx.x * NWAVE * 4];
            if (g == g0) {
#pragma unroll
                for (int i = 0; i < 8; i++) atomicAdd(&lsum[q * 8 + i], acc[i]);
                if (q == 0) atomicAdd(&lcnt, 1);
            } else {  // rare boundary node: direct global
#pragma unroll
                for (int i = 0; i < 8; i++) atomicAdd(&sums[g * HIDDEN + q * 8 + i], acc[i]);
                if (q == 0) atomicAdd(&counts[g], 1.0f);
            }
        }
        __syncthreads();
        int g0 = batch[blockIdx.x * NWAVE * 4];
        if (threadIdx.x < HIDDEN) atomicAdd(&sums[g0 * HIDDEN + threadIdx.x], lsum[threadIdx.x]);
        if (threadIdx.x == 0) atomicAdd(&counts[g0], (float)lcnt);
    }
}

// ---------------- final: out[g,o] = (sums[g,:]/max(cnt,1)) @ fcW + fcb -------------
__global__ __launch_bounds__(64) void k_final(const float* __restrict__ sums,
                                              const float* __restrict__ counts,
                                              const float* __restrict__ fcW,
                                              const float* __restrict__ fcb,
                                              float* __restrict__ out) {
    int g = blockIdx.x;
    int o = threadIdx.x;
    if (o >= OUT_DIM) return;
    float inv = 1.0f / fmaxf(counts[g], 1.0f);
    float acc = 0.f;
    for (int f = 0; f < HIDDEN; f++)
        acc = fmaf(sums[g * HIDDEN + f], fcW[f * OUT_DIM + o], acc);
    out[g * OUT_DIM + o] = acc * inv + fcb[o];
}

extern "C" void kernel_launch(void* const* d_in, const int* in_sizes, int n_in,
                              void* d_out, int out_size, void* d_ws, size_t ws_size,
                              hipStream_t stream) {
    const float* x      = (const float*)d_in[0];
    const float* ew     = (const float*)d_in[1];
    const float* emb    = (const float*)d_in[2];
    const float* W1     = (const float*)d_in[3];
    const float* b1     = (const float*)d_in[4];
    const float* W2     = (const float*)d_in[5];
    const float* b2     = (const float*)d_in[6];
    const float* fcW    = (const float*)d_in[7];
    const float* fcb    = (const float*)d_in[8];
    const int* edge_idx = (const int*)d_in[9];
    const int* batch    = (const int*)d_in[10];
    const int* node_ids = (const int*)d_in[11];
    float* out = (float*)d_out;

    const int* src = edge_idx;             // edge_index[0]
    const int* dst = edge_idx + N_EDGES;   // edge_index[1]

    // workspace layout (float units; bf16 buffers 16B-aligned)
    float* ws     = (float*)d_ws;
    float* dinv   = ws;                                        // 50048
    unsigned long long* dc = (unsigned long long*)(ws + 50048);// 50000 u64 = 100000 f
    int*   cursor = (int*)(ws + 150048);                       // 50048
    int*   rowptr = (int*)(ws + 200096);                       // 50056
    int*   bsum   = (int*)(ws + 250152);                       // 256
    int2*  csr    = (int2*)(ws + 250408);                      // 500000 int2 = 1M f
    unsigned short* tbf   = (unsigned short*)(ws + 1250408);   // 6.4M bf16 = 3.2M f
    unsigned short* out1b = (unsigned short*)(ws + 4450408);   // 6.4M bf16 (h1)
    float* sums   = ws + 7650408;                              // 8192
    float* counts = sums + N_GRAPHS * HIDDEN;                  // 64
    unsigned short* wt1 = (unsigned short*)(ws + 7658664);     // 147456 bf16
    unsigned short* wt2 = (unsigned short*)(ws + 7732392);     // 16384 bf16
    // end ~7740584 floats = 31 MB

    const int NB_EDGE = (N_EDGES + 255) / 256;           // 1954
    const int NB_GEMM = (N_NODES + 127) / 128;           // 391
    const int NB_AGG  = (N_NODES + 15) / 16;             // 3125 (16 nodes/block)
    const int K1 = N_FEAT + EMB_DIM;                     // 1152

    // preprocessing: packed degrees, multi-block scan, CSR, weights
    k_init <<<NB_NODE, 256, 0, stream>>>(dc, sums, counts);
    k_deg  <<<NB_EDGE, 256, 0, stream>>>(dst, ew, dc);
    k_scan1<<<NB_NODE, 256, 0, stream>>>(dc, bsum);
    k_scan2<<<1, 256, 0, stream>>>(bsum);
    k_scan3<<<NB_NODE, 256, 0, stream>>>(dc, bsum, cursor, rowptr, dinv);
    k_fill <<<NB_EDGE, 256, 0, stream>>>(src, dst, ew, dinv, cursor, csr);
    k_prep <<<40, 256, 0, stream>>>(W1, wt1, W2, wt2);

    // conv1: t1 = [x|emb] @ W1 (bf16) ; h1 = relu(aggregate + self + b1) (bf16)
    k_gemm<0><<<NB_GEMM, 256, 0, stream>>>(x, nullptr, emb, node_ids, wt1, tbf, K1);
    k_agg<0, 4><<<NB_AGG, 256, 0, stream>>>(csr, rowptr, dinv, tbf, b1,
                                            batch, out1b, sums, counts);

    // conv2: t2 = h1 @ W2 (bf16) ; fused aggregate+relu+pool
    k_gemm<1><<<NB_GEMM, 256, 0, stream>>>(nullptr, out1b, nullptr, nullptr, wt2, tbf, HIDDEN);
    k_agg<1, 4><<<NB_AGG, 256, 0, stream>>>(csr, rowptr, dinv, tbf, b2,
                                            batch, nullptr, sums, counts);

    // classifier
    k_final<<<N_GRAPHS, 64, 0, stream>>>(sums, counts, fcW, fcb, out);
}